// Round 2
// baseline (559.419 us; speedup 1.0000x reference)
//
#include <hip/hip_runtime.h>
#include <hip/hip_bf16.h>
#include <math.h>

typedef __hip_bfloat16 bf;

#define BB   16     // batch
#define CC   128    // channels
#define LL   4096   // H*W
#define DM   32     // d_model per chunk
#define DI   64     // d_inner
#define DSN  16     // d_state
#define GG   64     // 4 * BB sequences
#define NC   32     // scan chunks
#define CL   128    // LL / NC
#define TL   64     // l-tile for k1
#define NCOLK1 (TL + 3)
#define TL6  32     // l-tile for k6

__device__ __forceinline__ float bf2f(bf x) { return __bfloat162float(x); }
__device__ __forceinline__ bf f2bf(float x) { return __float2bfloat16(x); }
__device__ __forceinline__ float blo(unsigned v) { return __uint_as_float(v << 16); }
__device__ __forceinline__ float bhi(unsigned v) { return __uint_as_float(v & 0xffff0000u); }
__device__ __forceinline__ unsigned pack2(float a, float b) {
  bf ba = f2bf(a), bb = f2bf(b);
  unsigned short ua = *(unsigned short*)&ba, ub = *(unsigned short*)&bb;
  return (unsigned)ua | ((unsigned)ub << 16);
}

#if __has_builtin(__builtin_amdgcn_exp2f)
#define EXP2F(x) __builtin_amdgcn_exp2f(x)
#else
#define EXP2F(x) exp2f(x)
#endif

__device__ __forceinline__ float sigmoidf_(float x) { return 1.0f / (1.0f + __expf(-x)); }
__device__ __forceinline__ float softplusf_(float x) {
  return fmaxf(x, 0.0f) + log1pf(__expf(-fabsf(x)));
}
__device__ __forceinline__ void unpack8(uint4 v, float* o) {
  o[0] = blo(v.x); o[1] = bhi(v.x); o[2] = blo(v.y); o[3] = bhi(v.y);
  o[4] = blo(v.z); o[5] = bhi(v.z); o[6] = blo(v.w); o[7] = bhi(v.w);
}

// ---------------- K1: layernorm + in_proj(xi half) + causal conv + silu -> u (bf16) ----------------
// grid: BB * (LL/TL) = 1024 blocks, 256 threads. thread = (g, d).
__global__ __launch_bounds__(256) void k1_ln_conv(
    const float* __restrict__ input, const float* __restrict__ ln_g, const float* __restrict__ ln_b,
    const float* __restrict__ in_proj_w, const float* __restrict__ conv_w, const float* __restrict__ conv_b,
    bf* __restrict__ u_ws) {
  __shared__ float xnT[NCOLK1][132];   // [col j][channel c], stride 132 -> rows 16B-aligned
  __shared__ float mu_s[NCOLK1], rs_s[NCOLK1];
  int b = blockIdx.x >> 6;
  int tile = blockIdx.x & 63;
  int l0 = tile * TL;
  int tid = threadIdx.x;
  const float* inb = input + (size_t)b * CC * LL;
  for (int i = tid; i < CC * NCOLK1; i += 256) {
    int c = i / NCOLK1, j = i - c * NCOLK1;
    int l = l0 - 3 + j;
    xnT[j][c] = (l >= 0) ? inb[c * LL + l] : 0.0f;
  }
  __syncthreads();
  if (tid < NCOLK1) {
    float s = 0.f, s2 = 0.f;
    for (int c = 0; c < CC; c++) { float v = xnT[tid][c]; s += v; s2 = fmaf(v, v, s2); }
    float mu = s * (1.0f / CC);
    float var = s2 * (1.0f / CC) - mu * mu;
    mu_s[tid] = mu;
    rs_s[tid] = rsqrtf(var + 1e-5f);
  }
  __syncthreads();
  for (int i = tid; i < CC * NCOLK1; i += 256) {
    int c = i / NCOLK1, j = i - c * NCOLK1;
    xnT[j][c] = (xnT[j][c] - mu_s[j]) * rs_s[j] * ln_g[c] + ln_b[c];
  }
  __syncthreads();
  int g = tid >> 6, d = tid & 63;
  float w[32];
#pragma unroll
  for (int r = 0; r < 32; r++) w[r] = in_proj_w[d * DM + r];
  float cw0 = conv_w[d * 4 + 0], cw1 = conv_w[d * 4 + 1];
  float cw2 = conv_w[d * 4 + 2], cw3 = conv_w[d * 4 + 3];
  float cb = conv_b[d];
  int s_idx = g * BB + b;
  bf* uo = u_ws + (size_t)s_idx * LL * DI;
  float x3 = 0.f, x2 = 0.f, x1 = 0.f, x0 = 0.f;
  for (int j = 0; j < NCOLK1; j++) {
    int l = l0 - 3 + j;
    float xi = 0.f;
    if (l >= 0) {
      const float4* xp4 = (const float4*)&xnT[j][g * DM];  // wave-uniform addr -> broadcast
      float acc = 0.f;
#pragma unroll
      for (int q = 0; q < 8; q++) {
        float4 v = xp4[q];
        acc += v.x * w[q * 4 + 0] + v.y * w[q * 4 + 1] + v.z * w[q * 4 + 2] + v.w * w[q * 4 + 3];
      }
      xi = acc;
    }
    x3 = x2; x2 = x1; x1 = x0; x0 = xi;
    if (l >= l0) {
      float pre = x3 * cw0 + x2 * cw1 + x1 * cw2 + x0 * cw3 + cb;
      float uu = pre * sigmoidf_(pre);
      uo[(size_t)l * DI + d] = f2bf(uu);
    }
  }
}

// ---------------- K2: x_proj + dt_proj + softplus -> delta, B, C (bf16) ----------------
// grid: GG*LL/256 = 1024 blocks, 256 threads; one position per thread.
__global__ __launch_bounds__(256) void k2_xproj(
    const bf* __restrict__ u_ws, const float* __restrict__ x_proj_w,
    const float* __restrict__ dt_proj_w, const float* __restrict__ dt_proj_b,
    bf* __restrict__ delta_ws, bf* __restrict__ Bws, bf* __restrict__ Cws) {
  int pos = blockIdx.x * 256 + threadIdx.x;
  const uint4* up4 = (const uint4*)(u_ws + (size_t)pos * DI);
  float u[DI];
#pragma unroll
  for (int q = 0; q < 8; q++) unpack8(up4[q], &u[q * 8]);

  float xdb[34];
  for (int e = 0; e < 34; e++) {          // weights wave-uniform -> scalar loads
    float acc = 0.f;
#pragma unroll
    for (int dp = 0; dp < DI; dp++) acc += u[dp] * x_proj_w[e * DI + dp];
    xdb[e] = acc;
  }
  unsigned* Bo = (unsigned*)(Bws + (size_t)pos * DSN);
  unsigned* Co = (unsigned*)(Cws + (size_t)pos * DSN);
#pragma unroll
  for (int n = 0; n < 8; n++) Bo[n] = pack2(xdb[2 + 2 * n], xdb[3 + 2 * n]);
#pragma unroll
  for (int n = 0; n < 8; n++) Co[n] = pack2(xdb[18 + 2 * n], xdb[19 + 2 * n]);

  float dt0 = xdb[0], dt1 = xdb[1];
  unsigned* dout = (unsigned*)(delta_ws + (size_t)pos * DI);
  for (int d = 0; d < DI; d += 2) {
    float r0 = softplusf_(dt0 * dt_proj_w[2 * d + 0] + dt1 * dt_proj_w[2 * d + 1] + dt_proj_b[d]);
    float r1 = softplusf_(dt0 * dt_proj_w[2 * d + 2] + dt1 * dt_proj_w[2 * d + 3] + dt_proj_b[d + 1]);
    dout[d >> 1] = pack2(r0, r1);
  }
}

// ---------------- K3: scan pass A — local states + chunk transition products ----------------
// grid: GG*NC = 2048 blocks, 64 threads (1 wave, lane = d).
__global__ __launch_bounds__(64) void k3_scanA(
    const bf* __restrict__ delta_ws, const bf* __restrict__ u_ws, const bf* __restrict__ Bws,
    const float* __restrict__ A_log, float* __restrict__ hloc, float* __restrict__ Aprod) {
  int s = blockIdx.x / NC, chunk = blockIdx.x % NC;
  int d = threadIdx.x;
  float A2[DSN];
#pragma unroll
  for (int n = 0; n < DSN; n++)
    A2[n] = -__expf(A_log[d * DSN + n]) * 1.44269504088896f;  // A * log2(e)
  float h[DSN];
#pragma unroll
  for (int n = 0; n < DSN; n++) h[n] = 0.f;
  float ssum = 0.f;
  size_t base = (size_t)s * LL + (size_t)chunk * CL;
  const unsigned short* dp = (const unsigned short*)delta_ws + base * DI + d;
  const unsigned short* up = (const unsigned short*)u_ws + base * DI + d;
  const uint4* bp = (const uint4*)(Bws + base * DSN);
  for (int t = 0; t < CL; t++) {
    float delta = __uint_as_float((unsigned)dp[(size_t)t * DI] << 16);
    float uu    = __uint_as_float((unsigned)up[(size_t)t * DI] << 16);
    float Bv[16];
    unpack8(bp[t * 2], Bv); unpack8(bp[t * 2 + 1], Bv + 8);
    float du = delta * uu;
    ssum += delta;
#pragma unroll
    for (int n = 0; n < DSN; n++) {
      float e = EXP2F(delta * A2[n]);
      h[n] = fmaf(h[n], e, du * Bv[n]);
    }
  }
  size_t ob = (size_t)blockIdx.x * (DSN * DI) + d;
#pragma unroll
  for (int n = 0; n < DSN; n++) {
    hloc[ob + n * DI] = h[n];
    Aprod[ob + n * DI] = EXP2F(A2[n] * ssum);
  }
}

// ---------------- K4: sequential cross-chunk combine -> per-chunk initial states ----------------
// grid: GG blocks, 64 threads.
__global__ __launch_bounds__(64) void k4_combine(
    const float* __restrict__ hloc, const float* __restrict__ Aprod, float* __restrict__ hin) {
  int s = blockIdx.x, d = threadIdx.x;
  float h[DSN];
#pragma unroll
  for (int n = 0; n < DSN; n++) h[n] = 0.f;
  for (int k = 0; k < NC; k++) {
    size_t base = (size_t)(s * NC + k) * (DSN * DI) + d;
#pragma unroll
    for (int n = 0; n < DSN; n++) {
      hin[base + n * DI] = h[n];
      h[n] = fmaf(h[n], Aprod[base + n * DI], hloc[base + n * DI]);
    }
  }
}

// ---------------- K5: scan pass C — replay with h_in, emit y2 = y + u*D (bf16) ----------------
// grid: GG*NC = 2048 blocks, 64 threads.
__global__ __launch_bounds__(64) void k5_scanC(
    const bf* __restrict__ delta_ws, const bf* __restrict__ u_ws,
    const bf* __restrict__ Bws, const bf* __restrict__ Cws,
    const float* __restrict__ A_log, const float* __restrict__ Dw,
    const float* __restrict__ hin, bf* __restrict__ y2ws) {
  int s = blockIdx.x / NC, chunk = blockIdx.x % NC;
  int d = threadIdx.x;
  float A2[DSN];
#pragma unroll
  for (int n = 0; n < DSN; n++)
    A2[n] = -__expf(A_log[d * DSN + n]) * 1.44269504088896f;
  float Dd = Dw[d];
  float h[DSN];
  size_t hb = (size_t)blockIdx.x * (DSN * DI) + d;
#pragma unroll
  for (int n = 0; n < DSN; n++) h[n] = hin[hb + n * DI];
  size_t base = (size_t)s * LL + (size_t)chunk * CL;
  const unsigned short* dp = (const unsigned short*)delta_ws + base * DI + d;
  const unsigned short* up = (const unsigned short*)u_ws + base * DI + d;
  const uint4* bp = (const uint4*)(Bws + base * DSN);
  const uint4* cp = (const uint4*)(Cws + base * DSN);
  bf* yo = y2ws + base * DI + d;
  for (int t = 0; t < CL; t++) {
    float delta = __uint_as_float((unsigned)dp[(size_t)t * DI] << 16);
    float uu    = __uint_as_float((unsigned)up[(size_t)t * DI] << 16);
    float Bv[16], Cv[16];
    unpack8(bp[t * 2], Bv); unpack8(bp[t * 2 + 1], Bv + 8);
    unpack8(cp[t * 2], Cv); unpack8(cp[t * 2 + 1], Cv + 8);
    float du = delta * uu;
    float y = 0.f;
#pragma unroll
    for (int n = 0; n < DSN; n++) {
      float e = EXP2F(delta * A2[n]);
      h[n] = fmaf(h[n], e, du * Bv[n]);
      y = fmaf(h[n], Cv[n], y);
    }
    yo[(size_t)t * DI] = f2bf(y + uu * Dd);
  }
}

// ---------------- K6: layernorm (recompute) + z-gate + out_proj + residual -> output (fp32) ----------------
// grid: BB * (LL/TL6) = 2048 blocks, 256 threads.
__global__ __launch_bounds__(256) void k6_final(
    const float* __restrict__ input, const float* __restrict__ ln_g, const float* __restrict__ ln_b,
    const float* __restrict__ in_proj_w, const float* __restrict__ out_proj_w,
    const bf* __restrict__ y2ws, float* __restrict__ out) {
  __shared__ float xnT[TL6][132];
  __shared__ float mu_s[TL6], rs_s[TL6];
  __shared__ float y3T[4][TL6][65];   // [g][l][d]
  int b = blockIdx.x >> 7;
  int tile = blockIdx.x & 127;
  int l0 = tile * TL6;
  int tid = threadIdx.x;
  const float* inb = input + (size_t)b * CC * LL;
  for (int i = tid; i < CC * TL6; i += 256) {
    int c = i >> 5, j = i & 31;
    xnT[j][c] = inb[c * LL + l0 + j];
  }
  __syncthreads();
  if (tid < TL6) {
    float s = 0.f, s2 = 0.f;
    for (int c = 0; c < CC; c++) { float v = xnT[tid][c]; s += v; s2 = fmaf(v, v, s2); }
    float mu = s * (1.0f / CC);
    float var = s2 * (1.0f / CC) - mu * mu;
    mu_s[tid] = mu;
    rs_s[tid] = rsqrtf(var + 1e-5f);
  }
  __syncthreads();
  for (int i = tid; i < CC * TL6; i += 256) {
    int c = i >> 5, j = i & 31;
    xnT[j][c] = (xnT[j][c] - mu_s[j]) * rs_s[j] * ln_g[c] + ln_b[c];
  }
  __syncthreads();
  int g = tid >> 6, d = tid & 63;
  // z phase: thread (g, d), loop over columns
  {
    float wz[32];
#pragma unroll
    for (int r = 0; r < 32; r++) wz[r] = in_proj_w[(DI + d) * DM + r];
    int s_idx = g * BB + b;
    const unsigned short* yp = (const unsigned short*)y2ws + ((size_t)s_idx * LL + l0) * DI + d;
    for (int j = 0; j < TL6; j++) {
      const float4* xp4 = (const float4*)&xnT[j][g * DM];
      float acc = 0.f;
#pragma unroll
      for (int q = 0; q < 8; q++) {
        float4 v = xp4[q];
        acc += v.x * wz[q * 4 + 0] + v.y * wz[q * 4 + 1] + v.z * wz[q * 4 + 2] + v.w * wz[q * 4 + 3];
      }
      float z = acc;
      float y2 = __uint_as_float((unsigned)yp[(size_t)j * DI] << 16);
      y3T[g][j][d] = y2 * (z * sigmoidf_(z));
    }
  }
  __syncthreads();
  // out phase: thread = (g, half, l); each handles 16 of 32 output channels at one l
  {
    int lane = tid & 63;
    int l = lane & 31;
    int jj0 = (lane >> 5) * 16;
    float y3r[DI];
#pragma unroll
    for (int d2 = 0; d2 < DI; d2++) y3r[d2] = y3T[g][l][d2];
    float* ob = out + ((size_t)b * CC + g * DM) * LL + l0 + l;
    for (int jj = jj0; jj < jj0 + 16; jj++) {
      float acc = xnT[l][g * DM + jj];   // residual (xn chunk)
#pragma unroll
      for (int dp = 0; dp < DI; dp++) acc += y3r[dp] * out_proj_w[jj * DI + dp];  // uniform -> scalar
      ob[(size_t)jj * LL] = acc;
    }
  }
}

extern "C" void kernel_launch(void* const* d_in, const int* in_sizes, int n_in,
                              void* d_out, int out_size, void* d_ws, size_t ws_size,
                              hipStream_t stream) {
  const float* input     = (const float*)d_in[0];
  const float* ln_g      = (const float*)d_in[1];
  const float* ln_b      = (const float*)d_in[2];
  const float* in_proj_w = (const float*)d_in[3];
  const float* conv_w    = (const float*)d_in[4];
  const float* conv_b    = (const float*)d_in[5];
  const float* x_proj_w  = (const float*)d_in[6];
  const float* dt_proj_w = (const float*)d_in[7];
  const float* dt_proj_b = (const float*)d_in[8];
  const float* A_log     = (const float*)d_in[9];
  const float* Dw        = (const float*)d_in[10];
  const float* out_proj_w= (const float*)d_in[11];
  float* out = (float*)d_out;

  char* ws = (char*)d_ws;
  bf*    u_ws     = (bf*)(ws);                    // 262144*64 bf16 = 32 MiB
  bf*    delta_ws = (bf*)(ws + 33554432);         // 32 MiB
  bf*    Bws      = (bf*)(ws + 67108864);         // 8 MiB
  bf*    Cws      = (bf*)(ws + 75497472);         // 8 MiB
  bf*    y2ws     = (bf*)(ws + 83886080);         // 32 MiB
  float* hloc     = (float*)(ws + 117440512);     // 8 MiB
  float* Aprod    = (float*)(ws + 125829120);     // 8 MiB
  float* hin      = (float*)(ws + 134217728);     // 8 MiB
  (void)in_sizes; (void)n_in; (void)out_size; (void)ws_size;

  hipLaunchKernelGGL(k1_ln_conv, dim3(1024), dim3(256), 0, stream,
                     input, ln_g, ln_b, in_proj_w, conv_w, conv_b, u_ws);
  hipLaunchKernelGGL(k2_xproj, dim3(1024), dim3(256), 0, stream,
                     u_ws, x_proj_w, dt_proj_w, dt_proj_b, delta_ws, Bws, Cws);
  hipLaunchKernelGGL(k3_scanA, dim3(GG * NC), dim3(64), 0, stream,
                     delta_ws, u_ws, Bws, A_log, hloc, Aprod);
  hipLaunchKernelGGL(k4_combine, dim3(GG), dim3(64), 0, stream,
                     hloc, Aprod, hin);
  hipLaunchKernelGGL(k5_scanC, dim3(GG * NC), dim3(64), 0, stream,
                     delta_ws, u_ws, Bws, Cws, A_log, Dw, hin, y2ws);
  hipLaunchKernelGGL(k6_final, dim3(2048), dim3(256), 0, stream,
                     input, ln_g, ln_b, in_proj_w, out_proj_w, y2ws, out);
}